// Round 4
// baseline (1670.562 us; speedup 1.0000x reference)
//
#include <hip/hip_runtime.h>
#include <cfloat>
#include <climits>

// ---------------- problem constants ----------------
#define B_SZ   8
#define C2     128
#define C3     256
#define H2     28
#define W2     28
#define H3     14
#define W3     14
#define CDIM   384
#define N_EMB  (B_SZ*H2*W2)      // 6272 = 98 tiles of 64
#define M_BANK 30000
#define MP2    30208             // padded to multiple of 256
#define NT256  (MP2/256)         // 118 m-tiles of 256
#define IMGSZ  224
#define GY     16                // M-split for dist-min GEMM
#define TOPK   9
#define SPLIT  32                // per-b segments for top-k
#define LDSROW 392               // 384 + 8 bf16 pad (784B rows -> balanced LDS quads)

typedef __attribute__((ext_vector_type(8))) short short8v;   // bf16x8 bits (4 VGPR)
typedef __attribute__((ext_vector_type(4))) float f32x4;

// ---------------- bf16 split helpers ----------------
__device__ __forceinline__ ushort f2bf(float x) {
  union { float f; unsigned u; } a; a.f = x;
  const unsigned r = a.u + 0x7fffu + ((a.u >> 16) & 1u);   // RNE
  return (ushort)(r >> 16);
}
__device__ __forceinline__ float bf2f(ushort b) {
  union { float f; unsigned u; } a; a.u = ((unsigned)b) << 16;
  return a.f;
}

// ---------------- embedding build ----------------
// feat2 [B,128,28,28] -> avgpool3(zero-pad,/9) -> embT[C][N] rows 0..127
__global__ __launch_bounds__(256) void pool2_kernel(const float* __restrict__ feat2,
                                                    float* __restrict__ embT) {
  const int bc = blockIdx.x;            // b*128+c
  const int b = bc >> 7, c = bc & 127;
  __shared__ float plane[H2*W2];
  const float* src = feat2 + (size_t)bc * (H2*W2);
  for (int i = threadIdx.x; i < H2*W2; i += 256) plane[i] = src[i];
  __syncthreads();
  for (int i = threadIdx.x; i < H2*W2; i += 256) {
    const int h = i / W2, w = i % W2;
    float s = 0.f;
    #pragma unroll
    for (int dh = -1; dh <= 1; ++dh)
      #pragma unroll
      for (int dw = -1; dw <= 1; ++dw) {
        const int hh = h + dh, ww = w + dw;
        if (hh >= 0 && hh < H2 && ww >= 0 && ww < W2) s += plane[hh*W2 + ww];
      }
    embT[(size_t)c * N_EMB + (size_t)b * (H2*W2) + i] = s * (1.0f/9.0f);
  }
}

// feat3 [B,256,14,14] -> avgpool3 -> 2x bilinear -> embT rows 128..383
__global__ __launch_bounds__(256) void pool3up_kernel(const float* __restrict__ feat3,
                                                      float* __restrict__ embT) {
  const int bc = blockIdx.x;            // b*256+c
  const int b = bc >> 8, c = bc & 255;
  __shared__ float plane[H3*W3];
  __shared__ float pooled[H3*W3];
  const float* src = feat3 + (size_t)bc * (H3*W3);
  for (int i = threadIdx.x; i < H3*W3; i += 256) plane[i] = src[i];
  __syncthreads();
  for (int i = threadIdx.x; i < H3*W3; i += 256) {
    const int h = i / W3, w = i % W3;
    float s = 0.f;
    #pragma unroll
    for (int dh = -1; dh <= 1; ++dh)
      #pragma unroll
      for (int dw = -1; dw <= 1; ++dw) {
        const int hh = h + dh, ww = w + dw;
        if (hh >= 0 && hh < H3 && ww >= 0 && ww < W3) s += plane[hh*W3 + ww];
      }
    pooled[i] = s * (1.0f/9.0f);
  }
  __syncthreads();
  for (int i = threadIdx.x; i < H2*W2; i += 256) {
    const int h = i / W2, w = i % W2;
    const float sy = h*0.5f - 0.25f, sx = w*0.5f - 0.25f;
    const int y0 = (int)floorf(sy), x0 = (int)floorf(sx);
    const float fy = sy - y0, fx = sx - x0;
    const int y0c = min(max(y0, 0), H3-1),   y1c = min(max(y0+1, 0), H3-1);
    const int x0c = min(max(x0, 0), W3-1),   x1c = min(max(x0+1, 0), W3-1);
    const float v =
        (1.f-fy)*((1.f-fx)*pooled[y0c*W3+x0c] + fx*pooled[y0c*W3+x1c]) +
             fy *((1.f-fx)*pooled[y1c*W3+x0c] + fx*pooled[y1c*W3+x1c]);
    embT[(size_t)(C2 + c) * N_EMB + (size_t)b * (H2*W2) + i] = v;
  }
}

// transpose+convert: embT[C][N] f32 -> ehi/elo [N][C] bf16
__global__ __launch_bounds__(256) void embconv(const float* __restrict__ embT,
                                               ushort* __restrict__ eh,
                                               ushort* __restrict__ el) {
  __shared__ float tile[32][33];
  const int tid = threadIdx.x;
  const int n0 = blockIdx.x*32, c0 = blockIdx.y*32;
  #pragma unroll
  for (int p = 0; p < 4; ++p) {
    const int c = p*8 + (tid >> 5);
    const int n = tid & 31;
    tile[n][c] = embT[(size_t)(c0 + c)*N_EMB + n0 + n];
  }
  __syncthreads();
  const int nr = tid >> 3, cq = (tid & 7) << 2;
  ushort4 h, l;
  float v0 = tile[nr][cq+0], v1 = tile[nr][cq+1], v2 = tile[nr][cq+2], v3 = tile[nr][cq+3];
  h.x = f2bf(v0); h.y = f2bf(v1); h.z = f2bf(v2); h.w = f2bf(v3);
  l.x = f2bf(v0 - bf2f(h.x)); l.y = f2bf(v1 - bf2f(h.y));
  l.z = f2bf(v2 - bf2f(h.z)); l.w = f2bf(v3 - bf2f(h.w));
  *(ushort4*)&eh[(size_t)(n0+nr)*CDIM + c0 + cq] = h;
  *(ushort4*)&el[(size_t)(n0+nr)*CDIM + c0 + cq] = l;
}

// bank f32 [30000][384] -> bh/bl bf16 [MP2][384] (pad rows zero)
__global__ __launch_bounds__(256) void conv_bank(const float* __restrict__ bank,
                                                 ushort* __restrict__ bh,
                                                 ushort* __restrict__ bl) {
  const size_t i = (size_t)blockIdx.x*256 + threadIdx.x;   // one float4 per thread
  if (i >= (size_t)MP2*CDIM/4) return;
  const size_t e = i*4;
  const int row = (int)(e / CDIM);
  ushort4 h = {0,0,0,0}, l = {0,0,0,0};
  if (row < M_BANK) {
    const float4 v = *(const float4*)&bank[e];
    h.x = f2bf(v.x); h.y = f2bf(v.y); h.z = f2bf(v.z); h.w = f2bf(v.w);
    l.x = f2bf(v.x - bf2f(h.x)); l.y = f2bf(v.y - bf2f(h.y));
    l.z = f2bf(v.z - bf2f(h.z)); l.w = f2bf(v.w - bf2f(h.w));
  }
  *(ushort4*)&bh[e] = h;
  *(ushort4*)&bl[e] = l;
}

// ---------------- norms ----------------
__global__ void xn_kernel(const float* __restrict__ embT, float* __restrict__ xn) {
  const int n = blockIdx.x*256 + threadIdx.x;
  if (n >= N_EMB) return;
  float s = 0.f;
  for (int c = 0; c < CDIM; ++c) {
    const float v = embT[(size_t)c * N_EMB + n];
    s = fmaf(v, v, s);
  }
  xn[n] = s;
}

// one wave per bank row; padded rows get +inf-ish
__global__ void yn_kernel(const float* __restrict__ bank, float* __restrict__ yn) {
  const int wave = threadIdx.x >> 6, lane = threadIdx.x & 63;
  const int m = blockIdx.x*4 + wave;
  if (m >= MP2) return;
  if (m >= M_BANK) { if (lane == 0) yn[m] = 1e30f; return; }
  const float* row = bank + (size_t)m * CDIM;
  float s = 0.f;
  #pragma unroll
  for (int j = 0; j < CDIM/64; ++j) {
    const float v = row[lane + j*64];
    s = fmaf(v, v, s);
  }
  #pragma unroll
  for (int sh = 32; sh > 0; sh >>= 1) s += __shfl_down(s, sh);
  if (lane == 0) yn[m] = s;
}

// ---------------- fused distance GEMM (bf16-split MFMA) + min/argmin ----------------
// A = bank rows (M), B = emb cols (N). Block: 8 waves, n-tile 64 (LDS full-K),
// m-step 256 (8 waves x 32 rows). acc = hi*hi + hi*lo + lo*hi.
__global__ __launch_bounds__(512) void distmin_mfma(
    const ushort* __restrict__ ehi, const ushort* __restrict__ elo,
    const ushort* __restrict__ bhi, const ushort* __restrict__ blo,
    const float* __restrict__ xn,   const float* __restrict__ yn,
    float* __restrict__ pmin, int* __restrict__ parg)
{
  __shared__ ushort eshi[64*LDSROW];
  __shared__ ushort eslo[64*LDSROW];
  __shared__ float rv[8*64];
  __shared__ int   ri[8*64];

  const int tid = threadIdx.x;
  const int wave = tid >> 6, lane = tid & 63;
  const int lg = lane >> 4, lr = lane & 15;
  const int n0 = blockIdx.x * 64;

  // stage emb tile (hi+lo), full K, row-padded
  for (int idx = tid; idx < 64*48; idx += 512) {
    const int r = idx / 48, c8 = (idx % 48) * 8;
    *(short8v*)&eshi[r*LDSROW + c8] = *(const short8v*)&ehi[(size_t)(n0 + r)*CDIM + c8];
    *(short8v*)&eslo[r*LDSROW + c8] = *(const short8v*)&elo[(size_t)(n0 + r)*CDIM + c8];
  }
  __syncthreads();

  const int tilesPer = (NT256 + GY - 1) / GY;       // 8
  const int mt0 = blockIdx.y * tilesPer;
  const int mt1 = min(mt0 + tilesPer, NT256);

  float bestv[4]; int besti[4];
  #pragma unroll
  for (int t = 0; t < 4; ++t) { bestv[t] = FLT_MAX; besti[t] = INT_MAX; }

  for (int mt = mt0; mt < mt1; ++mt) {
    const int mbase = mt*256 + wave*32;
    f32x4 acc[2][4];
    #pragma unroll
    for (int f = 0; f < 2; ++f)
      #pragma unroll
      for (int t = 0; t < 4; ++t) acc[f][t] = (f32x4){0.f, 0.f, 0.f, 0.f};

    const ushort* a0h = bhi + (size_t)(mbase      + lr)*CDIM + lg*8;
    const ushort* a0l = blo + (size_t)(mbase      + lr)*CDIM + lg*8;
    const ushort* a1h = bhi + (size_t)(mbase + 16 + lr)*CDIM + lg*8;
    const ushort* a1l = blo + (size_t)(mbase + 16 + lr)*CDIM + lg*8;
    const int ebase = lr*LDSROW + lg*8;

    #pragma unroll
    for (int kc = 0; kc < 12; ++kc) {
      const int k0 = kc*32;
      const short8v va0h = *(const short8v*)&a0h[k0];
      const short8v va0l = *(const short8v*)&a0l[k0];
      const short8v va1h = *(const short8v*)&a1h[k0];
      const short8v va1l = *(const short8v*)&a1l[k0];
      #pragma unroll
      for (int t = 0; t < 4; ++t) {
        const short8v vbh = *(const short8v*)&eshi[ebase + t*16*LDSROW + k0];
        const short8v vbl = *(const short8v*)&eslo[ebase + t*16*LDSROW + k0];
        acc[0][t] = __builtin_amdgcn_mfma_f32_16x16x32_bf16(va0h, vbh, acc[0][t], 0, 0, 0);
        acc[0][t] = __builtin_amdgcn_mfma_f32_16x16x32_bf16(va0h, vbl, acc[0][t], 0, 0, 0);
        acc[0][t] = __builtin_amdgcn_mfma_f32_16x16x32_bf16(va0l, vbh, acc[0][t], 0, 0, 0);
        acc[1][t] = __builtin_amdgcn_mfma_f32_16x16x32_bf16(va1h, vbh, acc[1][t], 0, 0, 0);
        acc[1][t] = __builtin_amdgcn_mfma_f32_16x16x32_bf16(va1h, vbl, acc[1][t], 0, 0, 0);
        acc[1][t] = __builtin_amdgcn_mfma_f32_16x16x32_bf16(va1l, vbh, acc[1][t], 0, 0, 0);
      }
    }
    // epilogue: d2' = yn - 2*dot (xn added at write; same argmin)
    const int mrow = mbase + lg*4;
    #pragma unroll
    for (int f = 0; f < 2; ++f) {
      const float4 y4 = *(const float4*)&yn[mrow + f*16];
      const float yv[4] = {y4.x, y4.y, y4.z, y4.w};
      #pragma unroll
      for (int r = 0; r < 4; ++r) {
        const int m = mrow + f*16 + r;
        #pragma unroll
        for (int t = 0; t < 4; ++t) {
          const float d = yv[r] - 2.0f*acc[f][t][r];
          if (d < bestv[t]) { bestv[t] = d; besti[t] = m; }
        }
      }
    }
  }

  // cross-lane reduce (lanes holding same n: xor 16, 32), first-index ties
  #pragma unroll
  for (int t = 0; t < 4; ++t) {
    float v = bestv[t]; int bi = besti[t];
    #pragma unroll
    for (int off = 16; off < 64; off <<= 1) {
      const float ov = __shfl_xor(v, off);
      const int   oi = __shfl_xor(bi, off);
      if (ov < v || (ov == v && oi < bi)) { v = ov; bi = oi; }
    }
    if (lg == 0) { rv[wave*64 + t*16 + lr] = v; ri[wave*64 + t*16 + lr] = bi; }
  }
  __syncthreads();
  if (tid < 64) {
    float bv = rv[tid]; int bi = ri[tid];
    #pragma unroll
    for (int w = 1; w < 8; ++w) {
      const float v = rv[w*64 + tid]; const int ix = ri[w*64 + tid];
      if (v < bv || (v == bv && ix < bi)) { bv = v; bi = ix; }
    }
    pmin[(size_t)blockIdx.y*N_EMB + n0 + tid] = xn[n0 + tid] + bv;
    parg[(size_t)blockIdx.y*N_EMB + n0 + tid] = bi;
  }
}

// combine GY chunks -> patch score (sqrt) + location
__global__ void reduce_chunks(const float* __restrict__ pmin, const int* __restrict__ parg,
                              float* __restrict__ pscore, int* __restrict__ ploc) {
  const int n = blockIdx.x*256 + threadIdx.x;
  if (n >= N_EMB) return;
  float bv = pmin[n]; int bi = parg[n];
  for (int y = 1; y < GY; ++y) {
    const float v = pmin[(size_t)y*N_EMB + n];
    const int ix = parg[(size_t)y*N_EMB + n];
    if (v < bv || (v == bv && ix < bi)) { bv = v; bi = ix; }
  }
  pscore[n] = sqrtf(fmaxf(bv, 0.f));
  ploc[n] = bi;
}

// ---------------- per-batch argmax + gathers ----------------
__global__ __launch_bounds__(256) void perb_argmax(
    const float* __restrict__ pscore, const int* __restrict__ ploc,
    const float* __restrict__ embT,   const float* __restrict__ xn,
    float* __restrict__ scoreB, int* __restrict__ nnidx,
    float* __restrict__ maxfeat, float* __restrict__ mfnorm)
{
  const int b = blockIdx.x, tid = threadIdx.x;
  __shared__ float sv[256]; __shared__ int si[256];
  float bv = -FLT_MAX; int bi = INT_MAX;
  for (int p = tid; p < H2*W2; p += 256) {
    const float v = pscore[b*(H2*W2) + p];
    if (v > bv) { bv = v; bi = p; }
  }
  sv[tid] = bv; si[tid] = bi;
  __syncthreads();
  for (int s = 128; s > 0; s >>= 1) {
    if (tid < s) {
      if (sv[tid+s] > sv[tid] || (sv[tid+s] == sv[tid] && si[tid+s] < si[tid])) {
        sv[tid] = sv[tid+s]; si[tid] = si[tid+s];
      }
    }
    __syncthreads();
  }
  const int n = b*(H2*W2) + si[0];
  if (tid == 0) { scoreB[b] = sv[0]; nnidx[b] = ploc[n]; mfnorm[b] = xn[n]; }
  for (int c = tid; c < CDIM; c += 256) maxfeat[b*CDIM + c] = embT[(size_t)c*N_EMB + n];
}

// ---------------- per-batch 9-NN of nn_sample (partial, SPLIT segments) ----------------
__global__ __launch_bounds__(256) void topk_partial(
    const float* __restrict__ bank, const float* __restrict__ yn,
    const int* __restrict__ nnidx, float* __restrict__ candv, int* __restrict__ candi)
{
  const int b = blockIdx.y, seg = blockIdx.x, tid = threadIdx.x;
  __shared__ float nnf[CDIM];
  __shared__ float av[1024]; __shared__ int ai[1024];
  __shared__ float sv[256]; __shared__ int si[256]; __shared__ int sp[256];
  const int nni = nnidx[b];
  for (int c = tid; c < CDIM; c += 256) nnf[c] = bank[(size_t)nni*CDIM + c];
  __syncthreads();
  const float nn_norm = yn[nni];
  const int per = (M_BANK + SPLIT - 1) / SPLIT;   // 938
  const int mlo = seg * per;
  const int mhi = min(mlo + per, M_BANK);
  #pragma unroll
  for (int i = 0; i < 4; ++i) {
    const int m = mlo + i*256 + tid;
    float v = FLT_MAX; int ix = INT_MAX;
    if (m < mhi) {
      const float* row = bank + (size_t)m*CDIM;
      float dot = 0.f;
      for (int c = 0; c < CDIM; c += 4) {
        const float4 r4 = *reinterpret_cast<const float4*>(&row[c]);
        dot = fmaf(r4.x, nnf[c+0], dot);
        dot = fmaf(r4.y, nnf[c+1], dot);
        dot = fmaf(r4.z, nnf[c+2], dot);
        dot = fmaf(r4.w, nnf[c+3], dot);
      }
      v = nn_norm - 2.f*dot + yn[m];
      ix = m;
    }
    av[i*256 + tid] = v; ai[i*256 + tid] = ix;
  }
  __syncthreads();
  for (int r = 0; r < TOPK; ++r) {
    float bv = FLT_MAX; int bi = INT_MAX; int bp = -1;
    for (int p = tid; p < 1024; p += 256) {
      const float v = av[p]; const int ix = ai[p];
      if (v < bv || (v == bv && ix < bi)) { bv = v; bi = ix; bp = p; }
    }
    sv[tid] = bv; si[tid] = bi; sp[tid] = bp;
    __syncthreads();
    for (int s = 128; s > 0; s >>= 1) {
      if (tid < s) {
        if (sv[tid+s] < sv[tid] || (sv[tid+s] == sv[tid] && si[tid+s] < si[tid])) {
          sv[tid] = sv[tid+s]; si[tid] = si[tid+s]; sp[tid] = sp[tid+s];
        }
      }
      __syncthreads();
    }
    if (tid == 0) {
      candv[((size_t)b*SPLIT + seg)*TOPK + r] = sv[0];
      candi[((size_t)b*SPLIT + seg)*TOPK + r] = si[0];
      if (sp[0] >= 0) av[sp[0]] = FLT_MAX;
    }
    __syncthreads();
  }
}

// ---------------- merge candidates, compute pred_score ----------------
__global__ __launch_bounds__(320) void final_score(
    const float* __restrict__ bank, const float* __restrict__ yn,
    const float* __restrict__ candv, const int* __restrict__ candi,
    const float* __restrict__ maxfeat, const float* __restrict__ mfnorm,
    const float* __restrict__ scoreB, float* __restrict__ outp)
{
  const int b = blockIdx.x, tid = threadIdx.x;
  __shared__ float av[SPLIT*TOPK]; __shared__ int ai[SPLIT*TOPK];
  __shared__ int sup[TOPK];
  __shared__ float dist2[TOPK];
  if (tid < SPLIT*TOPK) {
    av[tid] = candv[(size_t)b*SPLIT*TOPK + tid];
    ai[tid] = candi[(size_t)b*SPLIT*TOPK + tid];
  }
  __syncthreads();
  if (tid == 0) {
    for (int r = 0; r < TOPK; ++r) {
      float bv = FLT_MAX; int bi = INT_MAX; int bp = -1;
      for (int p = 0; p < SPLIT*TOPK; ++p) {
        if (av[p] < bv || (av[p] == bv && ai[p] < bi)) { bv = av[p]; bi = ai[p]; bp = p; }
      }
      sup[r] = bi; av[bp] = FLT_MAX;
    }
  }
  __syncthreads();
  if (tid < TOPK*32) {
    const int j = tid >> 5, l = tid & 31;
    const float* row = bank + (size_t)sup[j]*CDIM;
    const float* mf  = maxfeat + b*CDIM;
    float p = 0.f;
    for (int c = l; c < CDIM; c += 32) p = fmaf(row[c], mf[c], p);
    #pragma unroll
    for (int s = 16; s > 0; s >>= 1) p += __shfl_down(p, s, 32);
    if (l == 0) dist2[j] = mfnorm[b] - 2.f*p + yn[sup[j]];
  }
  __syncthreads();
  if (tid == 0) {
    const float sc = scoreB[b];
    float se = 0.f;
    for (int j = 0; j < TOPK; ++j) se += expf(sqrtf(fmaxf(dist2[j], 0.f)));
    outp[b] = (1.f - expf(sc)/se) * sc;
  }
}

// ---------------- anomaly map: 28->224 bilinear then 33-tap separable gaussian ----------------
__global__ void resize_kernel(const float* __restrict__ pscore, float* __restrict__ amap) {
  const int idx = blockIdx.x*256 + threadIdx.x;
  if (idx >= B_SZ*IMGSZ*IMGSZ) return;
  const int b = idx / (IMGSZ*IMGSZ);
  const int r = idx % (IMGSZ*IMGSZ);
  const int oy = r / IMGSZ, ox = r % IMGSZ;
  const float sy = oy*0.125f - 0.4375f, sx = ox*0.125f - 0.4375f;
  const int y0 = (int)floorf(sy), x0 = (int)floorf(sx);
  const float fy = sy - y0, fx = sx - x0;
  const int y0c = min(max(y0, 0), H2-1), y1c = min(max(y0+1, 0), H2-1);
  const int x0c = min(max(x0, 0), W2-1), x1c = min(max(x0+1, 0), W2-1);
  const float* p = pscore + b*(H2*W2);
  amap[idx] = (1.f-fy)*((1.f-fx)*p[y0c*W2+x0c] + fx*p[y0c*W2+x1c]) +
                   fy *((1.f-fx)*p[y1c*W2+x0c] + fx*p[y1c*W2+x1c]);
}

__device__ __forceinline__ void make_gauss(float* kr, float* kinv, int tid) {
  if (tid < 33) { const float x = (tid - 16) * 0.25f; kr[tid] = expf(-0.5f*x*x); }
  __syncthreads();
  if (tid == 0) { float s = 0.f; for (int i = 0; i < 33; ++i) s += kr[i]; *kinv = 1.0f/s; }
  __syncthreads();
}

__global__ __launch_bounds__(256) void blurh_kernel(const float* __restrict__ amap,
                                                    float* __restrict__ tmp) {
  __shared__ float kr[33]; __shared__ float kinv; __shared__ float row[256];
  const int tid = threadIdx.x;
  make_gauss(kr, &kinv, tid);
  const int b = blockIdx.x / IMGSZ, y = blockIdx.x % IMGSZ;
  const float* src = amap + (size_t)(b*IMGSZ + y)*IMGSZ;
  const int xx = tid - 16;
  row[tid] = (xx >= 0 && xx < IMGSZ) ? src[xx] : 0.f;
  __syncthreads();
  if (tid < IMGSZ) {
    float s = 0.f;
    #pragma unroll
    for (int j = 0; j < 33; ++j) s = fmaf(kr[j], row[tid + j], s);
    tmp[(size_t)(b*IMGSZ + y)*IMGSZ + tid] = s * kinv;
  }
}

__global__ __launch_bounds__(256) void blurv_kernel(const float* __restrict__ tmp,
                                                    float* __restrict__ outp) {
  __shared__ float kr[33]; __shared__ float kinv;
  const int tid = threadIdx.x;
  make_gauss(kr, &kinv, tid);
  const int b = blockIdx.x / IMGSZ, y = blockIdx.x % IMGSZ;
  if (tid < IMGSZ) {
    float s = 0.f;
    #pragma unroll
    for (int j = 0; j < 33; ++j) {
      const int yy = y + j - 16;
      if (yy >= 0 && yy < IMGSZ) s = fmaf(kr[j], tmp[(size_t)(b*IMGSZ + yy)*IMGSZ + tid], s);
    }
    outp[(size_t)(b*IMGSZ + y)*IMGSZ + tid] = s * kinv;
  }
}

// ---------------- launch ----------------
extern "C" void kernel_launch(void* const* d_in, const int* in_sizes, int n_in,
                              void* d_out, int out_size, void* d_ws, size_t ws_size,
                              hipStream_t stream) {
  (void)in_sizes; (void)n_in; (void)out_size; (void)ws_size;
  const float* feat2 = (const float*)d_in[0];
  const float* feat3 = (const float*)d_in[1];
  const float* bank  = (const float*)d_in[2];
  float* out = (float*)d_out;

  char* w = (char*)d_ws;
  size_t off = 0;
  auto take = [&](size_t bytes) -> void* {
    void* p = w + off;
    off = (off + bytes + 255) & ~(size_t)255;
    return p;
  };
  float*  embT    = (float*) take(sizeof(float)*(size_t)CDIM*N_EMB);     // 9.6 MB
  ushort* ehi     = (ushort*)take(sizeof(ushort)*(size_t)N_EMB*CDIM);    // 4.8 MB
  ushort* elo     = (ushort*)take(sizeof(ushort)*(size_t)N_EMB*CDIM);
  ushort* bhi     = (ushort*)take(sizeof(ushort)*(size_t)MP2*CDIM);      // 23.2 MB
  ushort* blo     = (ushort*)take(sizeof(ushort)*(size_t)MP2*CDIM);
  float*  xn      = (float*) take(sizeof(float)*N_EMB);
  float*  yn      = (float*) take(sizeof(float)*MP2);
  float*  pmin    = (float*) take(sizeof(float)*(size_t)GY*N_EMB);
  int*    parg    = (int*)   take(sizeof(int)*(size_t)GY*N_EMB);
  float*  pscore  = (float*) take(sizeof(float)*N_EMB);
  int*    ploc    = (int*)   take(sizeof(int)*N_EMB);
  float*  scoreB  = (float*) take(sizeof(float)*B_SZ);
  int*    nnidx   = (int*)   take(sizeof(int)*B_SZ);
  float*  mfnorm  = (float*) take(sizeof(float)*B_SZ);
  float*  maxfeat = (float*) take(sizeof(float)*B_SZ*CDIM);
  float*  candv   = (float*) take(sizeof(float)*B_SZ*SPLIT*TOPK);
  int*    candi   = (int*)   take(sizeof(int)*B_SZ*SPLIT*TOPK);
  float*  amap    = (float*) take(sizeof(float)*(size_t)B_SZ*IMGSZ*IMGSZ);
  float*  tmpb    = (float*) take(sizeof(float)*(size_t)B_SZ*IMGSZ*IMGSZ);

  // embedding f32 [C][N] + bf16-split operands
  hipLaunchKernelGGL(pool2_kernel,   dim3(B_SZ*C2), dim3(256), 0, stream, feat2, embT);
  hipLaunchKernelGGL(pool3up_kernel, dim3(B_SZ*C3), dim3(256), 0, stream, feat3, embT);
  hipLaunchKernelGGL(embconv, dim3(N_EMB/32, CDIM/32), dim3(256), 0, stream, embT, ehi, elo);
  hipLaunchKernelGGL(conv_bank, dim3((unsigned)((size_t)MP2*CDIM/4/256)), dim3(256), 0, stream,
                     bank, bhi, blo);
  hipLaunchKernelGGL(xn_kernel, dim3((N_EMB+255)/256), dim3(256), 0, stream, embT, xn);
  hipLaunchKernelGGL(yn_kernel, dim3(MP2/4), dim3(256), 0, stream, bank, yn);

  // fused distance GEMM (MFMA) with min/argmin
  hipLaunchKernelGGL(distmin_mfma, dim3(N_EMB/64, GY), dim3(512), 0, stream,
                     ehi, elo, bhi, blo, xn, yn, pmin, parg);
  hipLaunchKernelGGL(reduce_chunks, dim3((N_EMB+255)/256), dim3(256), 0, stream,
                     pmin, parg, pscore, ploc);

  // pred_score path (exact f32)
  hipLaunchKernelGGL(perb_argmax, dim3(B_SZ), dim3(256), 0, stream,
                     pscore, ploc, embT, xn, scoreB, nnidx, maxfeat, mfnorm);
  hipLaunchKernelGGL(topk_partial, dim3(SPLIT, B_SZ), dim3(256), 0, stream,
                     bank, yn, nnidx, candv, candi);
  hipLaunchKernelGGL(final_score, dim3(B_SZ), dim3(320), 0, stream,
                     bank, yn, candv, candi, maxfeat, mfnorm, scoreB, out);

  // anomaly map path
  hipLaunchKernelGGL(resize_kernel, dim3((B_SZ*IMGSZ*IMGSZ+255)/256), dim3(256), 0, stream,
                     pscore, amap);
  hipLaunchKernelGGL(blurh_kernel, dim3(B_SZ*IMGSZ), dim3(256), 0, stream, amap, tmpb);
  hipLaunchKernelGGL(blurv_kernel, dim3(B_SZ*IMGSZ), dim3(256), 0, stream, tmpb, out + B_SZ);
}